// Round 12
// baseline (164.097 us; speedup 1.0000x reference)
//
#include <hip/hip_runtime.h>
#include <hip/hip_bf16.h>

#define TSEQ 2048
#define CEMB 1024

typedef __attribute__((ext_vector_type(8))) short bf16x8;
typedef __attribute__((ext_vector_type(4))) float f32x4;
typedef __attribute__((ext_vector_type(16))) float f32x16;
typedef __attribute__((ext_vector_type(4))) int i32x4;

__device__ __forceinline__ unsigned short f2bf(float f){
  return __builtin_bit_cast(unsigned short, __float2bfloat16(f));
}

__device__ __forceinline__ f32x4 MFMA16(bf16x8 a, bf16x8 b, f32x4 c){
  return __builtin_amdgcn_mfma_f32_16x16x32_bf16(a, b, c, 0, 0, 0);
}

#define GLDS(src, dst) __builtin_amdgcn_global_load_lds( \
      (const __attribute__((address_space(1))) void*)(src), \
      (__attribute__((address_space(3))) void*)(dst), 16, 0, 0)

template<int N> __device__ __forceinline__ void vmwait(){
  if constexpr (N == 0) asm volatile("s_waitcnt vmcnt(0)" ::: "memory");
  else if constexpr (N == 4) asm volatile("s_waitcnt vmcnt(4)" ::: "memory");
  else if constexpr (N == 5) asm volatile("s_waitcnt vmcnt(5)" ::: "memory");
  else if constexpr (N == 6) asm volatile("s_waitcnt vmcnt(6)" ::: "memory");
  else if constexpr (N == 7) asm volatile("s_waitcnt vmcnt(7)" ::: "memory");
  else asm volatile("s_waitcnt vmcnt(8)" ::: "memory");
}

// ---------- fused prep: x->bf16 cast + both weight transposes ----------
__global__ __launch_bounds__(256) void k_prep(
    const float* __restrict__ x, unsigned short* __restrict__ xb,
    const float* __restrict__ w_qkv, unsigned short* __restrict__ wqkvT,
    const float* __restrict__ w_out, unsigned short* __restrict__ woutT)
{
  __shared__ unsigned short tile[32][33];
  const int bid = blockIdx.x, tid = threadIdx.x;
  if (bid < 8192){
    const int i = bid * 256 + tid;
    const float4 v = reinterpret_cast<const float4*>(x)[i];
    ushort4 o;
    o.x = f2bf(v.x); o.y = f2bf(v.y); o.z = f2bf(v.z); o.w = f2bf(v.w);
    reinterpret_cast<ushort4*>(xb)[i] = o;
    return;
  }
  const float* w; unsigned short* wT; int N, n0, k0;
  if (bid < 11264){
    const int b2 = bid - 8192;           // 3072 blocks, N=3072
    w = w_qkv; wT = wqkvT; N = 3072;
    n0 = (b2 % 96) * 32; k0 = (b2 / 96) * 32;
  } else {
    const int b3 = bid - 11264;          // 1024 blocks, N=1024
    w = w_out; wT = woutT; N = 1024;
    n0 = (b3 & 31) * 32; k0 = (b3 >> 5) * 32;
  }
  const int tx = tid & 31, ty = tid >> 5;
  #pragma unroll
  for (int r = 0; r < 4; ++r){
    int k = ty * 4 + r;
    tile[k][tx] = f2bf(w[(size_t)(k0 + k) * N + n0 + tx]);
  }
  __syncthreads();
  #pragma unroll
  for (int r = 0; r < 4; ++r){
    int n = ty * 4 + r;
    wT[(size_t)(n0 + n) * 1024 + k0 + tx] = tile[tx][n];
  }
}

// ---------- V head-transpose: qkv[t][2048+h*64+d] -> vT[(bh*64+d)][t] ----------
__global__ __launch_bounds__(256) void k_vT(const unsigned short* __restrict__ qkv,
                                            unsigned short* __restrict__ vT){
  __shared__ __align__(16) unsigned short tile[64*64];
  const int tid = threadIdx.x;
  const int bh = blockIdx.x;          // b*16+h
  const int t0 = blockIdx.y * 64;
  const int b = bh >> 4, h = bh & 15;
  const int lt = tid >> 3, seg = tid & 7;
  #pragma unroll
  for (int r = 0; r < 2; ++r){
    const int t = lt + 32*r;
    const i32x4 v = *(const i32x4*)&qkv[((size_t)(b*TSEQ + t0 + t))*3072 + 2048 + h*64 + seg*8];
    const int slot = seg ^ (t & 7) ^ (t >> 3);
    *(i32x4*)((char*)tile + t*128 + slot*16) = v;
  }
  __syncthreads();
  const int w = tid >> 6, lane = tid & 63;
  const int tseg = lane & 7;
  #pragma unroll
  for (int r = 0; r < 2; ++r){
    const int d = w*8 + (lane>>3) + 32*r;
    unsigned int wd[4];
    #pragma unroll
    for (int jp = 0; jp < 4; ++jp){
      unsigned int lo, hi;
      #pragma unroll
      for (int e = 0; e < 2; ++e){
        const int j = jp*2 + e;
        const int t = tseg*8 + j;
        const int byteoff = t*128 + ((2*d) ^ (((j ^ tseg) & 7) << 4));
        const unsigned int val = *(const unsigned short*)((const char*)tile + byteoff);
        if (e == 0) lo = val; else hi = val;
      }
      wd[jp] = lo | (hi << 16);
    }
    i32x4 o4; o4[0]=wd[0]; o4[1]=wd[1]; o4[2]=wd[2]; o4[3]=wd[3];
    *(i32x4*)&vT[((size_t)bh*64 + d)*2048 + t0 + tseg*8] = o4;
  }
}

// ---------- GEMM BMxBN deep-pipelined (T1+T2+T3+T4+T5) ----------
// 512 thr = 8 waves (2M x 4N); per-wave (BM/2) x (BN/4); BK=64, two K-tiles
// in flight, raw s_barrier + counted vmcnt(NL). Content swizzle chunk^=row&7
// on global SOURCE (linear gload_lds dest) and on reads.
// BM=128,BN=192: LDS 80KB -> 2 blocks/CU (hides per-step barrier drain).
template<bool OUT_BF16, int BM, int BN>
__global__ __launch_bounds__(512, 2) void k_gemm256(
    const unsigned short* __restrict__ A,
    const unsigned short* __restrict__ Bt,
    const float* __restrict__ bias,
    void* __restrict__ Cout, int M, int N, int K)
{
  constexpr int NA  = BM / 64;          // A-stage insts per K-tile
  constexpr int NW  = BN / 64;          // per-wave n-frags AND B-stage insts
  constexpr int MM  = BM / 32;          // per-wave m-frags
  constexpr int MH  = MM / 2;
  constexpr int NH0 = (NW + 1) / 2;
  constexpr int NL  = NA + NW;          // loads in flight per K-tile
  constexpr int ABY = BM * 128;         // A buffer bytes per K-tile
  constexpr int BNB = BN * 128;         // B buffer bytes per K-tile
  __shared__ __align__(16) char smem[2*ABY + 2*BNB];

  const int tid = threadIdx.x;
  const int lane = tid & 63, w = tid >> 6;
  const int wm = w >> 2, wn = w & 3;
  const int l15 = lane & 15, l4 = lane >> 4;
  const int x7 = l15 & 7;

  unsigned lin = blockIdx.x;
  {
    const unsigned nwg = gridDim.x;
    const unsigned qq = nwg >> 3, rr = nwg & 7;
    const unsigned xcd = lin & 7, loc = lin >> 3;
    lin = (xcd < rr ? xcd * (qq + 1) : rr * (qq + 1) + (xcd - rr) * qq) + loc;
  }
  const unsigned ntn = (unsigned)N / BN;
  const int m0 = (int)(lin / ntn) * BM;
  const int n0 = (int)(lin % ntn) * BN;

  const int srow = lane >> 3;
  const int scx  = (lane & 7) ^ srow;
  const unsigned short* Ag = A  + (size_t)(m0 + w*8 + srow) * K + scx * 8;
  const unsigned short* Bg = Bt + (size_t)(n0 + w*8 + srow) * K + scx * 8;

  auto stageA = [&](int buf, int kt){
    const unsigned short* s = Ag + kt*64;
    char* d = smem + buf*ABY + (w << 10);
    #pragma unroll
    for (int i = 0; i < NA; ++i) GLDS(s + (size_t)(i*64)*K, d + i*8192);
  };
  auto stageB = [&](int buf, int kt){
    const unsigned short* s = Bg + kt*64;
    char* d = smem + 2*ABY + buf*BNB + (w << 10);
    #pragma unroll
    for (int i = 0; i < NW; ++i) GLDS(s + (size_t)(i*64)*K, d + i*8192);
  };

  const int arow = wm*(BM/2) + l15;
  const int brow = wn*(BN/4) + l15;
  auto rdA = [&](int buf, int m, int ks)->bf16x8 {
    return *(const bf16x8*)(smem + buf*ABY + (arow + m*16)*128 + (((ks*4 + l4) ^ x7) << 4));
  };
  auto rdB = [&](int buf, int n, int ks)->bf16x8 {
    return *(const bf16x8*)(smem + 2*ABY + buf*BNB + (brow + n*16)*128 + (((ks*4 + l4) ^ x7) << 4));
  };

  f32x4 acc[MM][NW] = {};
  const int NIT = K >> 7;

  stageA(0, 0); stageB(0, 0);
  stageA(1, 1); stageB(1, 1);
  vmwait<NL>();
  __builtin_amdgcn_s_barrier();
  asm volatile("" ::: "memory");

  for (int it = 0; it < NIT; ++it){
    const bool more = (it + 1 < NIT);
    #pragma unroll
    for (int half = 0; half < 2; ++half){
      const int buf = half;
      bf16x8 bfr[NW][2], af1[MH][2], af2[MM-MH][2];
      #pragma unroll
      for (int n = 0; n < NW; ++n){ bfr[n][0] = rdB(buf, n, 0); bfr[n][1] = rdB(buf, n, 1); }
      #pragma unroll
      for (int m = 0; m < MH; ++m){ af1[m][0] = rdA(buf, m, 0); af1[m][1] = rdA(buf, m, 1); }
      __builtin_amdgcn_s_setprio(1);
      #pragma unroll
      for (int m = 0; m < MH; ++m)
        #pragma unroll
        for (int n = 0; n < NH0; ++n)
          #pragma unroll
          for (int ks = 0; ks < 2; ++ks)
            acc[m][n] = MFMA16(af1[m][ks], bfr[n][ks], acc[m][n]);
      __builtin_amdgcn_s_setprio(0);
      #pragma unroll
      for (int m = 0; m < MM-MH; ++m){ af2[m][0] = rdA(buf, m+MH, 0); af2[m][1] = rdA(buf, m+MH, 1); }
      __builtin_amdgcn_s_setprio(1);
      #pragma unroll
      for (int m = 0; m < MH; ++m)
        #pragma unroll
        for (int n = NH0; n < NW; ++n)
          #pragma unroll
          for (int ks = 0; ks < 2; ++ks)
            acc[m][n] = MFMA16(af1[m][ks], bfr[n][ks], acc[m][n]);
      __builtin_amdgcn_s_setprio(0);
      __builtin_amdgcn_s_setprio(1);
      #pragma unroll
      for (int m = 0; m < MM-MH; ++m)
        #pragma unroll
        for (int n = NH0; n < NW; ++n)
          #pragma unroll
          for (int ks = 0; ks < 2; ++ks)
            acc[m+MH][n] = MFMA16(af2[m][ks], bfr[n][ks], acc[m+MH][n]);
      __builtin_amdgcn_s_setprio(0);
      asm volatile("s_waitcnt lgkmcnt(0)" ::: "memory");
      __builtin_amdgcn_s_barrier();
      asm volatile("" ::: "memory");
      if (more){ stageA(buf, 2*it + half + 2); stageB(buf, 2*it + half + 2); }
      __builtin_amdgcn_s_setprio(1);
      #pragma unroll
      for (int m = 0; m < MM-MH; ++m)
        #pragma unroll
        for (int n = 0; n < NH0; ++n)
          #pragma unroll
          for (int ks = 0; ks < 2; ++ks)
            acc[m+MH][n] = MFMA16(af2[m][ks], bfr[n][ks], acc[m+MH][n]);
      __builtin_amdgcn_s_setprio(0);
      if (more) vmwait<NL>();
      else      vmwait<0>();
      __builtin_amdgcn_s_barrier();
      asm volatile("" ::: "memory");
    }
  }

  float bv[NW];
  #pragma unroll
  for (int n = 0; n < NW; ++n) bv[n] = bias[n0 + wn*(BN/4) + n*16 + l15];

  #pragma unroll
  for (int m = 0; m < MM; ++m){
    const int row = m0 + wm*(BM/2) + m*16 + l4*4;
    #pragma unroll
    for (int n = 0; n < NW; ++n){
      const int col = n0 + wn*(BN/4) + n*16 + l15;
      #pragma unroll
      for (int r = 0; r < 4; ++r){
        float v = acc[m][n][r] + bv[n];
        if (OUT_BF16)
          ((unsigned short*)Cout)[(size_t)(row + r) * N + col] = f2bf(v);
        else
          ((float*)Cout)[(size_t)(row + r) * N + col] = v;
      }
    }
  }
}

// ---------- causal flash attention v9 = v8 + XCD-owned heads ----------
// Grid 512 (1D). Decode: xcd = lin&7 owns heads {xcd, xcd+8, ...} -> each
// XCD's L2 holds exactly 8 heads x 512KB K/V = 4MB; the 8 p-blocks of one
// head all land on the same XCD -> KV fetched from HBM ~once per head
// (R11 grid put them on 8 different XCDs -> FETCH 110MB).
__global__ __launch_bounds__(512, 3) void k_attn(
    const unsigned short* __restrict__ qkv,
    const unsigned short* __restrict__ vT,
    unsigned short* __restrict__ y)
{
  __shared__ __align__(16) char Ksm[2][8192];   // [key 64][128B], slot^=(key&7)
  __shared__ __align__(16) char Vsm[2][8192];   // [d 64][128B],  slot^=(d&7)
  __shared__ float Ls[8][32];

  const int tid = threadIdx.x, lane = tid & 63, w = tid >> 6;  // w 0..7
  const int q31 = lane & 31, hi = lane >> 5;
  const int lin = blockIdx.x;
  const int xcd = lin & 7, ii = lin >> 3;
  const int bh = xcd + ((ii & 7) << 3);         // head-group pinned to XCD
  const int p = ii >> 3;                        // p in [0,8)
  const int g = w >> 2, wl = w & 3;
  const int myt = g ? (15 - p) : p;             // this wavegroup's q-tile
  const int b = bh >> 4, h = bh & 15;
  const size_t rowB = (size_t)b * TSEQ;

  const int wq0 = myt*128 + 32*wl, qg = wq0 + q31;
  const int nkt_my = 2*myt + 2;
  const int nktB  = 2*(15 - p) + 2;             // loop bound (heavy tile)

  const float sc = 0.18033688011112042f;   // (1/sqrt(64)) * log2(e)

  bf16x8 qf[4];
  {
    const unsigned short* qp = qkv + (rowB + qg) * 3072 + h * 64;
    #pragma unroll
    for (int c4 = 0; c4 < 4; ++c4){
      bf16x8 v = *(const bf16x8*)(qp + c4*16 + hi*8);
      #pragma unroll
      for (int j = 0; j < 8; ++j){
        const unsigned int bits = ((unsigned int)(unsigned short)v[j]) << 16;
        v[j] = (short)f2bf(__builtin_bit_cast(float, bits) * sc);
      }
      qf[c4] = v;
    }
  }

  // shared staging: 512 thr cover 64 rows x 8 chunks of K and V exactly once
  const int kr = lane >> 3, cx = (lane & 7) ^ kr;
  const unsigned short* kgbase = qkv + (rowB + w*8 + kr) * 3072 + 1024 + h*64 + cx*8;
  const unsigned short* vgbase = vT + ((size_t)bh*64 + w*8 + kr) * 2048 + cx*8;

  #define STAGE(ktile, buf)                                                          \
    do {                                                                             \
      GLDS(kgbase + (size_t)(ktile)*64*3072, &Ksm[buf][0] + w*1024);                 \
      GLDS(vgbase + (ktile)*64,              &Vsm[buf][0] + w*1024);                 \
    } while (0)

  f32x16 O[2] = {};
  float l = 0.f;

  STAGE(0, 0);
  __syncthreads();

  int cbuf = 0;
  for (int kt = 0; kt < nktB; ++kt){
    if (kt + 1 < nktB) STAGE(kt + 1, cbuf ^ 1);

    if (kt < nkt_my){
      const char* kb = Ksm[cbuf];
      const char* vb = Vsm[cbuf];
      const bool domask = (kt*64 + 63 > wq0);
      #pragma unroll
      for (int sub = 0; sub < 2; ++sub){
        f32x16 S = {};
        __builtin_amdgcn_s_setprio(1);
        #pragma unroll
        for (int c4 = 0; c4 < 4; ++c4){
          const bf16x8 kf = *(const bf16x8*)(kb + (sub*32 + q31)*128
                                + ((((c4<<1)|hi) ^ (q31 & 7)) << 4));
          S = __builtin_amdgcn_mfma_f32_32x32x16_bf16(kf, qf[c4], S, 0, 0, 0);
        }
        __builtin_amdgcn_s_setprio(0);
        if (domask){
          #pragma unroll
          for (int r = 0; r < 16; ++r){
            const int kg = kt*64 + sub*32 + (r&3) + 8*(r>>2) + 4*hi;
            if (kg > qg) S[r] = -1e30f;
          }
        }
        float ps = 0.f;
        #pragma unroll
        for (int r = 0; r < 16; ++r){
          S[r] = __builtin_amdgcn_exp2f(S[r]);   // shift-free; cancels in 1/l
          ps += S[r];
        }
        l += ps;
        bf16x8 paf[2];
        #pragma unroll
        for (int kc = 0; kc < 2; ++kc){
          const int e = kc * 8;
          unsigned int a, bb, cc, dd;
          asm("v_cvt_pk_bf16_f32 %0, %1, %2" : "=v"(a)  : "v"(S[e+0]), "v"(S[e+1]));
          asm("v_cvt_pk_bf16_f32 %0, %1, %2" : "=v"(bb) : "v"(S[e+4]), "v"(S[e+5]));
          asm("v_cvt_pk_bf16_f32 %0, %1, %2" : "=v"(cc) : "v"(S[e+2]), "v"(S[e+3]));
          asm("v_cvt_pk_bf16_f32 %0, %1, %2" : "=v"(dd) : "v"(S[e+6]), "v"(S[e+7]));
          asm volatile("v_permlane32_swap_b32 %0, %1" : "+v"(a),  "+v"(bb));
          asm volatile("v_permlane32_swap_b32 %0, %1" : "+v"(cc), "+v"(dd));
          i32x4 pwv; pwv[0] = (int)a; pwv[1] = (int)cc; pwv[2] = (int)bb; pwv[3] = (int)dd;
          paf[kc] = __builtin_bit_cast(bf16x8, pwv);
        }
        __builtin_amdgcn_s_setprio(1);
        #pragma unroll
        for (int kc = 0; kc < 2; ++kc){
          #pragma unroll
          for (int dblk = 0; dblk < 2; ++dblk){
            const int dr = dblk*32 + q31;
            const bf16x8 vf = *(const bf16x8*)(vb + dr*128
                                  + ((((sub<<2)|(kc<<1)|hi) ^ (dr & 7)) << 4));
            O[dblk] = __builtin_amdgcn_mfma_f32_32x32x16_bf16(paf[kc], vf, O[dblk], 0, 0, 0);
          }
        }
        __builtin_amdgcn_s_setprio(0);
      }
    }

    __syncthreads();   // drains global_load_lds + publishes next buffer
    cbuf ^= 1;
  }

  {
    const float lc = l + __shfl_xor(l, 32);
    if (lane < 32) Ls[w][lane] = 1.0f / lc;
  }
  __syncthreads();

  #pragma unroll
  for (int r = 0; r < 16; ++r){
    const int qloc = (r&3) + 8*(r>>2) + 4*hi;
    const float inv = Ls[w][qloc];
    const size_t row = rowB + wq0 + qloc;
    #pragma unroll
    for (int dblk = 0; dblk < 2; ++dblk)
      y[row * CEMB + h*64 + dblk*32 + q31] = f2bf(O[dblk][r] * inv);
  }
  #undef STAGE
}

extern "C" void kernel_launch(void* const* d_in, const int* in_sizes, int n_in,
                              void* d_out, int out_size, void* d_ws, size_t ws_size,
                              hipStream_t stream)
{
  const float* x     = (const float*)d_in[0];
  const float* w_qkv = (const float*)d_in[1];
  const float* b_qkv = (const float*)d_in[2];
  const float* w_out = (const float*)d_in[3];
  const float* b_out = (const float*)d_in[4];
  float* out = (float*)d_out;

  char* ws = (char*)d_ws;
  unsigned short* xb    = (unsigned short*)(ws);                 // 16 MiB; dead after gemm1
  unsigned short* vTb   = (unsigned short*)(ws);                 // 16 MiB (reuses xb)
  unsigned short* qkvb  = (unsigned short*)(ws + (16u<<20));     // 48 MiB [8192,3072]
  unsigned short* yb    = (unsigned short*)(ws + (64u<<20));     // 16 MiB [8192,1024]
  unsigned short* wqkvT = (unsigned short*)(ws + (80u<<20));     //  6 MiB [3072,1024]
  unsigned short* woutT = (unsigned short*)(ws + (86u<<20));     //  2 MiB [1024,1024]

  const int M = 4 * TSEQ; // 8192

  k_prep<<<12288, 256, 0, stream>>>(x, xb, w_qkv, wqkvT, w_out, woutT);

  // QKV: 128x192 tiles, 80KB LDS -> 2 blocks/CU; 64*16 = 1024 blocks = 2 rounds
  k_gemm256<true, 128, 192><<<dim3((M/128) * (3072/192)), 512, 0, stream>>>(xb, wqkvT, b_qkv, qkvb, M, 3072, 1024);
  k_vT<<<dim3(64, TSEQ/64), 256, 0, stream>>>(qkvb, vTb);
  // attn: XCD-owned head groups (see k_attn header)
  k_attn<<<dim3(512), 512, 0, stream>>>(qkvb, vTb, yb);
  // out-proj: 128x128 tiles, 64KB LDS -> 2 blocks/CU; 64*8 = 512 blocks = 1 round
  k_gemm256<false, 128, 128><<<dim3((M/128) * (1024/128)), 512, 0, stream>>>(yb, woutT, b_out, out, M, 1024, 1024);
}

// Round 13
// 145.383 us; speedup vs baseline: 1.1287x; 1.1287x over previous
//
#include <hip/hip_runtime.h>
#include <hip/hip_bf16.h>

#define TSEQ 2048
#define CEMB 1024

typedef __attribute__((ext_vector_type(8))) short bf16x8;
typedef __attribute__((ext_vector_type(4))) float f32x4;
typedef __attribute__((ext_vector_type(16))) float f32x16;
typedef __attribute__((ext_vector_type(4))) int i32x4;

__device__ __forceinline__ unsigned short f2bf(float f){
  return __builtin_bit_cast(unsigned short, __float2bfloat16(f));
}

__device__ __forceinline__ f32x4 MFMA16(bf16x8 a, bf16x8 b, f32x4 c){
  return __builtin_amdgcn_mfma_f32_16x16x32_bf16(a, b, c, 0, 0, 0);
}

#define GLDS(src, dst) __builtin_amdgcn_global_load_lds( \
      (const __attribute__((address_space(1))) void*)(src), \
      (__attribute__((address_space(3))) void*)(dst), 16, 0, 0)

template<int N> __device__ __forceinline__ void vmwait(){
  if constexpr (N == 0) asm volatile("s_waitcnt vmcnt(0)" ::: "memory");
  else if constexpr (N == 4) asm volatile("s_waitcnt vmcnt(4)" ::: "memory");
  else if constexpr (N == 5) asm volatile("s_waitcnt vmcnt(5)" ::: "memory");
  else if constexpr (N == 6) asm volatile("s_waitcnt vmcnt(6)" ::: "memory");
  else if constexpr (N == 7) asm volatile("s_waitcnt vmcnt(7)" ::: "memory");
  else asm volatile("s_waitcnt vmcnt(8)" ::: "memory");
}

// ---------- fused prep: x->bf16 cast + both weight transposes ----------
__global__ __launch_bounds__(256) void k_prep(
    const float* __restrict__ x, unsigned short* __restrict__ xb,
    const float* __restrict__ w_qkv, unsigned short* __restrict__ wqkvT,
    const float* __restrict__ w_out, unsigned short* __restrict__ woutT)
{
  __shared__ unsigned short tile[32][33];
  const int bid = blockIdx.x, tid = threadIdx.x;
  if (bid < 8192){
    const int i = bid * 256 + tid;
    const float4 v = reinterpret_cast<const float4*>(x)[i];
    ushort4 o;
    o.x = f2bf(v.x); o.y = f2bf(v.y); o.z = f2bf(v.z); o.w = f2bf(v.w);
    reinterpret_cast<ushort4*>(xb)[i] = o;
    return;
  }
  const float* w; unsigned short* wT; int N, n0, k0;
  if (bid < 11264){
    const int b2 = bid - 8192;           // 3072 blocks, N=3072
    w = w_qkv; wT = wqkvT; N = 3072;
    n0 = (b2 % 96) * 32; k0 = (b2 / 96) * 32;
  } else {
    const int b3 = bid - 11264;          // 1024 blocks, N=1024
    w = w_out; wT = woutT; N = 1024;
    n0 = (b3 & 31) * 32; k0 = (b3 >> 5) * 32;
  }
  const int tx = tid & 31, ty = tid >> 5;
  #pragma unroll
  for (int r = 0; r < 4; ++r){
    int k = ty * 4 + r;
    tile[k][tx] = f2bf(w[(size_t)(k0 + k) * N + n0 + tx]);
  }
  __syncthreads();
  #pragma unroll
  for (int r = 0; r < 4; ++r){
    int n = ty * 4 + r;
    wT[(size_t)(n0 + n) * 1024 + k0 + tx] = tile[tx][n];
  }
}

// ---------- GEMM BMxBN deep-pipelined (T1+T2+T3+T4+T5) ----------
// FUSE_VT (QKV only): fragments in the V column range [2048,3072) are written
// TRANSPOSED to vT[(bh*64+d)*2048 + t] (packed ushort4: 4 consecutive t per
// lane) instead of to Cout — this replaces the separate k_vT kernel.
template<bool OUT_BF16, int BM, int BN, bool FUSE_VT>
__global__ __launch_bounds__(512, 2) void k_gemm256(
    const unsigned short* __restrict__ A,
    const unsigned short* __restrict__ Bt,
    const float* __restrict__ bias,
    void* __restrict__ Cout,
    unsigned short* __restrict__ vTout,
    int M, int N, int K)
{
  constexpr int NA  = BM / 64;          // A-stage insts per K-tile
  constexpr int NW  = BN / 64;          // per-wave n-frags AND B-stage insts
  constexpr int MM  = BM / 32;          // per-wave m-frags
  constexpr int MH  = MM / 2;
  constexpr int NH0 = (NW + 1) / 2;
  constexpr int NL  = NA + NW;          // loads in flight per K-tile
  constexpr int ABY = BM * 128;
  constexpr int BNB = BN * 128;
  __shared__ __align__(16) char smem[2*ABY + 2*BNB];

  const int tid = threadIdx.x;
  const int lane = tid & 63, w = tid >> 6;
  const int wm = w >> 2, wn = w & 3;
  const int l15 = lane & 15, l4 = lane >> 4;
  const int x7 = l15 & 7;

  unsigned lin = blockIdx.x;
  {
    const unsigned nwg = gridDim.x;
    const unsigned qq = nwg >> 3, rr = nwg & 7;
    const unsigned xcd = lin & 7, loc = lin >> 3;
    lin = (xcd < rr ? xcd * (qq + 1) : rr * (qq + 1) + (xcd - rr) * qq) + loc;
  }
  const unsigned ntn = (unsigned)N / BN;
  const int m0 = (int)(lin / ntn) * BM;
  const int n0 = (int)(lin % ntn) * BN;

  const int srow = lane >> 3;
  const int scx  = (lane & 7) ^ srow;
  const unsigned short* Ag = A  + (size_t)(m0 + w*8 + srow) * K + scx * 8;
  const unsigned short* Bg = Bt + (size_t)(n0 + w*8 + srow) * K + scx * 8;

  auto stageA = [&](int buf, int kt){
    const unsigned short* s = Ag + kt*64;
    char* d = smem + buf*ABY + (w << 10);
    #pragma unroll
    for (int i = 0; i < NA; ++i) GLDS(s + (size_t)(i*64)*K, d + i*8192);
  };
  auto stageB = [&](int buf, int kt){
    const unsigned short* s = Bg + kt*64;
    char* d = smem + 2*ABY + buf*BNB + (w << 10);
    #pragma unroll
    for (int i = 0; i < NW; ++i) GLDS(s + (size_t)(i*64)*K, d + i*8192);
  };

  const int arow = wm*(BM/2) + l15;
  const int brow = wn*(BN/4) + l15;
  auto rdA = [&](int buf, int m, int ks)->bf16x8 {
    return *(const bf16x8*)(smem + buf*ABY + (arow + m*16)*128 + (((ks*4 + l4) ^ x7) << 4));
  };
  auto rdB = [&](int buf, int n, int ks)->bf16x8 {
    return *(const bf16x8*)(smem + 2*ABY + buf*BNB + (brow + n*16)*128 + (((ks*4 + l4) ^ x7) << 4));
  };

  f32x4 acc[MM][NW] = {};
  const int NIT = K >> 7;

  stageA(0, 0); stageB(0, 0);
  stageA(1, 1); stageB(1, 1);
  vmwait<NL>();
  __builtin_amdgcn_s_barrier();
  asm volatile("" ::: "memory");

  for (int it = 0; it < NIT; ++it){
    const bool more = (it + 1 < NIT);
    #pragma unroll
    for (int half = 0; half < 2; ++half){
      const int buf = half;
      bf16x8 bfr[NW][2], af1[MH][2], af2[MM-MH][2];
      #pragma unroll
      for (int n = 0; n < NW; ++n){ bfr[n][0] = rdB(buf, n, 0); bfr[n][1] = rdB(buf, n, 1); }
      #pragma unroll
      for (int m = 0; m < MH; ++m){ af1[m][0] = rdA(buf, m, 0); af1[m][1] = rdA(buf, m, 1); }
      __builtin_amdgcn_s_setprio(1);
      #pragma unroll
      for (int m = 0; m < MH; ++m)
        #pragma unroll
        for (int n = 0; n < NH0; ++n)
          #pragma unroll
          for (int ks = 0; ks < 2; ++ks)
            acc[m][n] = MFMA16(af1[m][ks], bfr[n][ks], acc[m][n]);
      __builtin_amdgcn_s_setprio(0);
      #pragma unroll
      for (int m = 0; m < MM-MH; ++m){ af2[m][0] = rdA(buf, m+MH, 0); af2[m][1] = rdA(buf, m+MH, 1); }
      __builtin_amdgcn_s_setprio(1);
      #pragma unroll
      for (int m = 0; m < MH; ++m)
        #pragma unroll
        for (int n = NH0; n < NW; ++n)
          #pragma unroll
          for (int ks = 0; ks < 2; ++ks)
            acc[m][n] = MFMA16(af1[m][ks], bfr[n][ks], acc[m][n]);
      __builtin_amdgcn_s_setprio(0);
      __builtin_amdgcn_s_setprio(1);
      #pragma unroll
      for (int m = 0; m < MM-MH; ++m)
        #pragma unroll
        for (int n = NH0; n < NW; ++n)
          #pragma unroll
          for (int ks = 0; ks < 2; ++ks)
            acc[m+MH][n] = MFMA16(af2[m][ks], bfr[n][ks], acc[m+MH][n]);
      __builtin_amdgcn_s_setprio(0);
      asm volatile("s_waitcnt lgkmcnt(0)" ::: "memory");
      __builtin_amdgcn_s_barrier();
      asm volatile("" ::: "memory");
      if (more){ stageA(buf, 2*it + half + 2); stageB(buf, 2*it + half + 2); }
      __builtin_amdgcn_s_setprio(1);
      #pragma unroll
      for (int m = 0; m < MM-MH; ++m)
        #pragma unroll
        for (int n = 0; n < NH0; ++n)
          #pragma unroll
          for (int ks = 0; ks < 2; ++ks)
            acc[m+MH][n] = MFMA16(af2[m][ks], bfr[n][ks], acc[m+MH][n]);
      __builtin_amdgcn_s_setprio(0);
      if (more) vmwait<NL>();
      else      vmwait<0>();
      __builtin_amdgcn_s_barrier();
      asm volatile("" ::: "memory");
    }
  }

  float bv[NW];
  #pragma unroll
  for (int n = 0; n < NW; ++n) bv[n] = bias[n0 + wn*(BN/4) + n*16 + l15];

  #pragma unroll
  for (int m = 0; m < MM; ++m){
    const int row = m0 + wm*(BM/2) + m*16 + l4*4;
    #pragma unroll
    for (int n = 0; n < NW; ++n){
      const int colb = n0 + wn*(BN/4) + n*16;
      if (FUSE_VT && colb >= 2048){
        // V fragment -> transposed store: vT[(bh*64+d)*2048 + t], 4 t's packed
        const int c = colb - 2048 + l15;        // h*64 + d
        const int bb = row >> 11, tt = row & 2047;
        ushort4 pk;
        pk.x = f2bf(acc[m][n][0] + bv[n]);
        pk.y = f2bf(acc[m][n][1] + bv[n]);
        pk.z = f2bf(acc[m][n][2] + bv[n]);
        pk.w = f2bf(acc[m][n][3] + bv[n]);
        *(ushort4*)&vTout[(((size_t)bb*16)*64 + c)*2048 + tt] = pk;
      } else {
        const int col = colb + l15;
        #pragma unroll
        for (int r = 0; r < 4; ++r){
          float v = acc[m][n][r] + bv[n];
          if (OUT_BF16)
            ((unsigned short*)Cout)[(size_t)(row + r) * N + col] = f2bf(v);
          else
            ((float*)Cout)[(size_t)(row + r) * N + col] = v;
        }
      }
    }
  }
}

// ---------- causal flash attention v9 (unchanged from round 12) ----------
// Grid 512 (1D). xcd = lin&7 owns heads {xcd, xcd+8, ...} -> per-XCD KV
// working set = 8 heads x 512KB = 4MB = one L2.
__global__ __launch_bounds__(512, 3) void k_attn(
    const unsigned short* __restrict__ qkv,
    const unsigned short* __restrict__ vT,
    unsigned short* __restrict__ y)
{
  __shared__ __align__(16) char Ksm[2][8192];   // [key 64][128B], slot^=(key&7)
  __shared__ __align__(16) char Vsm[2][8192];   // [d 64][128B],  slot^=(d&7)
  __shared__ float Ls[8][32];

  const int tid = threadIdx.x, lane = tid & 63, w = tid >> 6;  // w 0..7
  const int q31 = lane & 31, hi = lane >> 5;
  const int lin = blockIdx.x;
  const int xcd = lin & 7, ii = lin >> 3;
  const int bh = xcd + ((ii & 7) << 3);         // head-group pinned to XCD
  const int p = ii >> 3;                        // p in [0,8)
  const int g = w >> 2, wl = w & 3;
  const int myt = g ? (15 - p) : p;             // this wavegroup's q-tile
  const int b = bh >> 4, h = bh & 15;
  const size_t rowB = (size_t)b * TSEQ;

  const int wq0 = myt*128 + 32*wl, qg = wq0 + q31;
  const int nkt_my = 2*myt + 2;
  const int nktB  = 2*(15 - p) + 2;             // loop bound (heavy tile)

  const float sc = 0.18033688011112042f;   // (1/sqrt(64)) * log2(e)

  bf16x8 qf[4];
  {
    const unsigned short* qp = qkv + (rowB + qg) * 3072 + h * 64;
    #pragma unroll
    for (int c4 = 0; c4 < 4; ++c4){
      bf16x8 v = *(const bf16x8*)(qp + c4*16 + hi*8);
      #pragma unroll
      for (int j = 0; j < 8; ++j){
        const unsigned int bits = ((unsigned int)(unsigned short)v[j]) << 16;
        v[j] = (short)f2bf(__builtin_bit_cast(float, bits) * sc);
      }
      qf[c4] = v;
    }
  }

  const int kr = lane >> 3, cx = (lane & 7) ^ kr;
  const unsigned short* kgbase = qkv + (rowB + w*8 + kr) * 3072 + 1024 + h*64 + cx*8;
  const unsigned short* vgbase = vT + ((size_t)bh*64 + w*8 + kr) * 2048 + cx*8;

  #define STAGE(ktile, buf)                                                          \
    do {                                                                             \
      GLDS(kgbase + (size_t)(ktile)*64*3072, &Ksm[buf][0] + w*1024);                 \
      GLDS(vgbase + (ktile)*64,              &Vsm[buf][0] + w*1024);                 \
    } while (0)

  f32x16 O[2] = {};
  float l = 0.f;

  STAGE(0, 0);
  __syncthreads();

  int cbuf = 0;
  for (int kt = 0; kt < nktB; ++kt){
    if (kt + 1 < nktB) STAGE(kt + 1, cbuf ^ 1);

    if (kt < nkt_my){
      const char* kb = Ksm[cbuf];
      const char* vb = Vsm[cbuf];
      const bool domask = (kt*64 + 63 > wq0);
      #pragma unroll
      for (int sub = 0; sub < 2; ++sub){
        f32x16 S = {};
        __builtin_amdgcn_s_setprio(1);
        #pragma unroll
        for (int c4 = 0; c4 < 4; ++c4){
          const bf16x8 kf = *(const bf16x8*)(kb + (sub*32 + q31)*128
                                + ((((c4<<1)|hi) ^ (q31 & 7)) << 4));
          S = __builtin_amdgcn_mfma_f32_32x32x16_bf16(kf, qf[c4], S, 0, 0, 0);
        }
        __builtin_amdgcn_s_setprio(0);
        if (domask){
          #pragma unroll
          for (int r = 0; r < 16; ++r){
            const int kg = kt*64 + sub*32 + (r&3) + 8*(r>>2) + 4*hi;
            if (kg > qg) S[r] = -1e30f;
          }
        }
        float ps = 0.f;
        #pragma unroll
        for (int r = 0; r < 16; ++r){
          S[r] = __builtin_amdgcn_exp2f(S[r]);   // shift-free; cancels in 1/l
          ps += S[r];
        }
        l += ps;
        bf16x8 paf[2];
        #pragma unroll
        for (int kc = 0; kc < 2; ++kc){
          const int e = kc * 8;
          unsigned int a, bb, cc, dd;
          asm("v_cvt_pk_bf16_f32 %0, %1, %2" : "=v"(a)  : "v"(S[e+0]), "v"(S[e+1]));
          asm("v_cvt_pk_bf16_f32 %0, %1, %2" : "=v"(bb) : "v"(S[e+4]), "v"(S[e+5]));
          asm("v_cvt_pk_bf16_f32 %0, %1, %2" : "=v"(cc) : "v"(S[e+2]), "v"(S[e+3]));
          asm("v_cvt_pk_bf16_f32 %0, %1, %2" : "=v"(dd) : "v"(S[e+6]), "v"(S[e+7]));
          asm volatile("v_permlane32_swap_b32 %0, %1" : "+v"(a),  "+v"(bb));
          asm volatile("v_permlane32_swap_b32 %0, %1" : "+v"(cc), "+v"(dd));
          i32x4 pwv; pwv[0] = (int)a; pwv[1] = (int)cc; pwv[2] = (int)bb; pwv[3] = (int)dd;
          paf[kc] = __builtin_bit_cast(bf16x8, pwv);
        }
        __builtin_amdgcn_s_setprio(1);
        #pragma unroll
        for (int kc = 0; kc < 2; ++kc){
          #pragma unroll
          for (int dblk = 0; dblk < 2; ++dblk){
            const int dr = dblk*32 + q31;
            const bf16x8 vf = *(const bf16x8*)(vb + dr*128
                                  + ((((sub<<2)|(kc<<1)|hi) ^ (dr & 7)) << 4));
            O[dblk] = __builtin_amdgcn_mfma_f32_32x32x16_bf16(paf[kc], vf, O[dblk], 0, 0, 0);
          }
        }
        __builtin_amdgcn_s_setprio(0);
      }
    }

    __syncthreads();   // drains global_load_lds + publishes next buffer
    cbuf ^= 1;
  }

  {
    const float lc = l + __shfl_xor(l, 32);
    if (lane < 32) Ls[w][lane] = 1.0f / lc;
  }
  __syncthreads();

  #pragma unroll
  for (int r = 0; r < 16; ++r){
    const int qloc = (r&3) + 8*(r>>2) + 4*hi;
    const float inv = Ls[w][qloc];
    const size_t row = rowB + wq0 + qloc;
    #pragma unroll
    for (int dblk = 0; dblk < 2; ++dblk)
      y[row * CEMB + h*64 + dblk*32 + q31] = f2bf(O[dblk][r] * inv);
  }
  #undef STAGE
}

extern "C" void kernel_launch(void* const* d_in, const int* in_sizes, int n_in,
                              void* d_out, int out_size, void* d_ws, size_t ws_size,
                              hipStream_t stream)
{
  const float* x     = (const float*)d_in[0];
  const float* w_qkv = (const float*)d_in[1];
  const float* b_qkv = (const float*)d_in[2];
  const float* w_out = (const float*)d_in[3];
  const float* b_out = (const float*)d_in[4];
  float* out = (float*)d_out;

  // liveness-packed workspace (88 MiB total):
  //   @0   : xb (prep -> QKV read), then yb (attn write -> outproj read)
  //   @16M : qkvb (QKV write Q|K -> attn read)
  //   @64M : vTb  (QKV epilogue write -> attn read)
  //   @80M : wqkvT, @86M : woutT
  char* ws = (char*)d_ws;
  unsigned short* xb    = (unsigned short*)(ws);
  unsigned short* yb    = (unsigned short*)(ws);                 // reuses xb slot
  unsigned short* qkvb  = (unsigned short*)(ws + (16u<<20));
  unsigned short* vTb   = (unsigned short*)(ws + (64u<<20));
  unsigned short* wqkvT = (unsigned short*)(ws + (80u<<20));
  unsigned short* woutT = (unsigned short*)(ws + (86u<<20));

  const int M = 4 * TSEQ; // 8192

  k_prep<<<12288, 256, 0, stream>>>(x, xb, w_qkv, wqkvT, w_out, woutT);

  // QKV: 256x192 tiles (proven config) + fused V^T epilogue; 512 blocks
  k_gemm256<true, 256, 192, true><<<dim3((M/256) * (3072/192)), 512, 0, stream>>>(
      xb, wqkvT, b_qkv, qkvb, vTb, M, 3072, 1024);
  // attn: XCD-owned head groups
  k_attn<<<dim3(512), 512, 0, stream>>>(qkvb, vTb, yb);
  // out-proj: 128x128 tiles, 64KB LDS -> 2 blocks/CU; 512 blocks = 1 round
  k_gemm256<false, 128, 128, false><<<dim3((M/128) * (1024/128)), 512, 0, stream>>>(
      yb, woutT, b_out, out, nullptr, M, 1024, 1024);
}